// Round 14
// baseline (191.781 us; speedup 1.0000x reference)
//
#include <hip/hip_runtime.h>
#include <math.h>

#define BH 64
#define NN 8192
#define DD 64
#define MM 32

#define NROWS (BH*NN)            // 524288
#define NORMC 0.35355339059327379f   // 64^-0.25
#define RATIO 0.17677669529663689f   // 32^-0.5
#define EPSK  1e-4f
#define DIAGC 0.0625f                // 0.5 * 64^-0.5

#define CPB 32                   // chunks per batch
#define CHUNK 256                // rows per chunk
#define K12_BLOCKS (BH*CPB)      // 2048

typedef __attribute__((ext_vector_type(8))) short short8;
typedef __attribute__((ext_vector_type(4))) float f32x4;

union FragU { uint4 u; short8 s; };

// round-to-nearest-even fp32 -> bf16 (bits in low 16)
__device__ __forceinline__ unsigned bf16r(float x) {
  unsigned u = __float_as_uint(x);
  return (u + 0x7fffu + ((u >> 16) & 1u)) >> 16;
}
// 8 fp32 -> hi/lo bf16x8 fragments (split: x = hi + lo)
__device__ __forceinline__ void cvt8(const float* f, FragU& hi, FragU& lo) {
  unsigned h[8], lw[8];
  #pragma unroll
  for (int j = 0; j < 8; ++j) {
    h[j] = bf16r(f[j]);
    lw[j] = bf16r(f[j] - __uint_as_float(h[j] << 16));
  }
  hi.u = make_uint4(h[0]|(h[1]<<16),  h[2]|(h[3]<<16),  h[4]|(h[5]<<16),  h[6]|(h[7]<<16));
  lo.u = make_uint4(lw[0]|(lw[1]<<16), lw[2]|(lw[3]<<16), lw[4]|(lw[5]<<16), lw[6]|(lw[7]<<16));
}

#define MFMA(a,b,c) __builtin_amdgcn_mfma_f32_16x16x32_bf16((a),(b),(c),0,0,0)

__device__ __forceinline__ float wave_max(float v) {
  #pragma unroll
  for (int off = 32; off > 0; off >>= 1)
    v = fmaxf(v, __shfl_down(v, off, 64));
  return v;
}

// ---------------- proj fragments: hi/lo bf16x8 per (mt,ks,lane) -------------
// B-frag (16x16x32): lane l holds B[k=(l>>4)*8+j][n=l&15]; B = proj^T so
// value = proj[mt*16 + (l&15)][ks*32 + (l>>4)*8 + j].
__global__ void kfrag_proj(const float* __restrict__ proj,
                           uint4* __restrict__ pfH, uint4* __restrict__ pfL)
{
  const int t = threadIdx.x;
  const int l = t & 63, g = t >> 6;          // g = mt*2 + ks
  const int mt = g >> 1, ks = g & 1;
  const int lr = l & 15, lg = l >> 4;
  float f[8];
  #pragma unroll
  for (int j = 0; j < 8; ++j)
    f[j] = proj[(mt*16 + lr)*DD + ks*32 + lg*8 + j];
  FragU hi, lo; cvt8(f, hi, lo);
  pfH[g*64 + l] = hi.u;
  pfL[g*64 + l] = lo.u;
}

// ---------------- K12: FUSED — dash MFMA -> E' (LDS bf16) -> kv MFMA --------
// R14: occupancy push. Grid 2048 (wave = 64 rows = 2 nb) restores backfill;
// launch_bounds(256,4) with the R12 register diet (~116 total incl AGPR,
// <=128 budget) doubles waves/SIMD 2->4. WRITE_SIZE is the spill canary
// (legit ~18 MB; ballooning means the bound must revert to (256,3)).
__global__ __launch_bounds__(256, 4) void k12_kv(
    const float* __restrict__ k, const float* __restrict__ v,
    const uint4* __restrict__ pfH, const uint4* __restrict__ pfL,
    float* __restrict__ kvPart, float* __restrict__ ksPart,
    float* __restrict__ vsPart, float* __restrict__ partialMax)
{
  __shared__ float red[8192];      // 32 KB: aliased E' staging, then reductions
  __shared__ float wmaxL[4];
  const int t = threadIdx.x;
  const int w = t >> 6, l = t & 63;
  const int lr = l & 15, lg = l >> 4;
  const int blk = blockIdx.x;
  const int b = blk >> 5, c = blk & (CPB - 1);
  const size_t gbase = (size_t)b * NN + (size_t)c * CHUNK + (size_t)w * 64;

  ushort* eh = (ushort*)red + w * 2560;   // [32 m][40] hi  (2560B/wave)
  ushort* el = eh + 1280;                 // [32 m][40] lo

  FragU pbH[2][2], pbL[2][2];
  #pragma unroll
  for (int mt = 0; mt < 2; ++mt)
    #pragma unroll
    for (int ks = 0; ks < 2; ++ks) {
      pbH[mt][ks].u = pfH[(mt*2+ks)*64 + l];
      pbL[mt][ks].u = pfL[(mt*2+ks)*64 + l];
    }

  f32x4 accK[2][4];
  #pragma unroll
  for (int mt = 0; mt < 2; ++mt)
    #pragma unroll
    for (int dt = 0; dt < 4; ++dt)
      accK[mt][dt] = (f32x4){0.f, 0.f, 0.f, 0.f};
  float ksacc0 = 0.f, ksacc1 = 0.f;
  float vsum[4] = {0.f, 0.f, 0.f, 0.f};
  float tmax = -3.4e38f;

  for (int nb = 0; nb < 2; ++nb) {
    const size_t nrow0 = gbase + nb * 32;

    // ---- phase A: E' for the nb's 32 rows (MFMA dash), staged to LDS
    #pragma unroll
    for (int rt = 0; rt < 2; ++rt) {
      float sq = 0.f;
      f32x4 a0 = {0.f,0.f,0.f,0.f}, a1 = {0.f,0.f,0.f,0.f};
      #pragma unroll
      for (int ks = 0; ks < 2; ++ks) {
        const float4* src = (const float4*)(k + (nrow0 + rt*16 + lr)*DD + ks*32 + lg*8);
        float4 x0 = src[0], x1 = src[1];
        float qv[8] = {x0.x,x0.y,x0.z,x0.w, x1.x,x1.y,x1.z,x1.w};
        #pragma unroll
        for (int j = 0; j < 8; ++j) sq += qv[j]*qv[j];
        FragU aH, aL; cvt8(qv, aH, aL);     // live only inside this ks
        a0 = MFMA(aL.s, pbH[0][ks].s, a0);
        a0 = MFMA(aH.s, pbL[0][ks].s, a0);
        a0 = MFMA(aH.s, pbH[0][ks].s, a0);
        a1 = MFMA(aL.s, pbH[1][ks].s, a1);
        a1 = MFMA(aH.s, pbL[1][ks].s, a1);
        a1 = MFMA(aH.s, pbH[1][ks].s, a1);
      }
      sq += __shfl_xor(sq, 16, 64);
      sq += __shfl_xor(sq, 32, 64);
      unsigned h0w[4], l0w[4], h1w[4], l1w[4];
      #pragma unroll
      for (int reg = 0; reg < 4; ++reg) {
        const float diag = DIAGC * __shfl(sq, lg*4 + reg, 64);
        const float d0 = a0[reg] * NORMC;
        const float d1 = a1[reg] * NORMC;
        tmax = fmaxf(tmax, fmaxf(d0, d1));
        const float e0 = __expf(d0 - diag);
        const float e1 = __expf(d1 - diag);
        ksacc0 += e0;                      // col m = lr
        ksacc1 += e1;                      // col m = lr+16
        h0w[reg] = bf16r(e0);
        l0w[reg] = bf16r(e0 - __uint_as_float(h0w[reg] << 16));
        h1w[reg] = bf16r(e1);
        l1w[reg] = bf16r(e1 - __uint_as_float(h1w[reg] << 16));
      }
      const int nloc = rt*16 + lg*4;       // 4 consecutive ushorts, 4B-aligned
      *(unsigned*)(eh + lr*40      + nloc)     = h0w[0] | (h0w[1] << 16);
      *(unsigned*)(eh + lr*40      + nloc + 2) = h0w[2] | (h0w[3] << 16);
      *(unsigned*)(el + lr*40      + nloc)     = l0w[0] | (l0w[1] << 16);
      *(unsigned*)(el + lr*40      + nloc + 2) = l0w[2] | (l0w[3] << 16);
      *(unsigned*)(eh + (lr+16)*40 + nloc)     = h1w[0] | (h1w[1] << 16);
      *(unsigned*)(eh + (lr+16)*40 + nloc + 2) = h1w[2] | (h1w[3] << 16);
      *(unsigned*)(el + (lr+16)*40 + nloc)     = l1w[0] | (l1w[1] << 16);
      *(unsigned*)(el + (lr+16)*40 + nloc + 2) = l1w[2] | (l1w[3] << 16);
    }

    // ---- phase B: kv += E'^T x v via MFMA (A from LDS, B from global)
    #pragma unroll
    for (int dt = 0; dt < 4; ++dt) {
      float vv[8];
      #pragma unroll
      for (int j = 0; j < 8; ++j)
        vv[j] = v[(nrow0 + lg*8 + j)*DD + dt*16 + lr];
      vsum[dt] += vv[0]+vv[1]+vv[2]+vv[3]+vv[4]+vv[5]+vv[6]+vv[7];
      FragU bHv, bLv; cvt8(vv, bHv, bLv);
      #pragma unroll
      for (int mt = 0; mt < 2; ++mt) {
        FragU aHk, aLk;
        aHk.u = *(const uint4*)(eh + (mt*16 + lr)*40 + lg*8);
        aLk.u = *(const uint4*)(el + (mt*16 + lr)*40 + lg*8);
        accK[mt][dt] = MFMA(aLk.s, bHv.s, accK[mt][dt]);
        accK[mt][dt] = MFMA(aHk.s, bLv.s, accK[mt][dt]);
        accK[mt][dt] = MFMA(aHk.s, bHv.s, accK[mt][dt]);
      }
    }
  }

  // ---- epilogue: block max + reductions
  tmax = wave_max(tmax);
  if (l == 0) wmaxL[w] = tmax;
  ksacc0 += __shfl_xor(ksacc0, 16, 64);
  ksacc0 += __shfl_xor(ksacc0, 32, 64);
  ksacc1 += __shfl_xor(ksacc1, 16, 64);
  ksacc1 += __shfl_xor(ksacc1, 32, 64);
  #pragma unroll
  for (int dt = 0; dt < 4; ++dt) {
    vsum[dt] += __shfl_xor(vsum[dt], 16, 64);
    vsum[dt] += __shfl_xor(vsum[dt], 32, 64);
  }
  __syncthreads();                 // everyone done with E' staging
  // red layout [o][w] (o = m*64+d): lanes same inst -> banks 4lr+w, 2-way max
  #pragma unroll
  for (int mt = 0; mt < 2; ++mt)
    #pragma unroll
    for (int dt = 0; dt < 4; ++dt)
      #pragma unroll
      for (int reg = 0; reg < 4; ++reg)
        red[((mt*16 + lg*4 + reg)*64 + dt*16 + lr)*4 + w] = accK[mt][dt][reg];
  __syncthreads();
  if (t == 0)
    partialMax[blk] = fmaxf(fmaxf(wmaxL[0], wmaxL[1]), fmaxf(wmaxL[2], wmaxL[3]));
  #pragma unroll
  for (int ii = 0; ii < 8; ++ii) {
    const int o = t + 256 * ii;
    const float4 r4 = *(const float4*)&red[o*4];
    kvPart[(size_t)blk * 2048 + o] = r4.x + r4.y + r4.z + r4.w;
  }
  __syncthreads();
  if (l < 16) {
    red[w*32 + lr]        = ksacc0;
    red[w*32 + 16 + lr]   = ksacc1;
    #pragma unroll
    for (int dt = 0; dt < 4; ++dt)
      red[128 + w*64 + dt*16 + lr] = vsum[dt];
  }
  __syncthreads();
  if (t < 32)
    ksPart[blk*32 + t] = red[t] + red[32+t] + red[64+t] + red[96+t];
  if (t < 64)
    vsPart[blk*64 + t] = red[128+t] + red[192+t] + red[256+t] + red[320+t];
}

// ---------------- K1b: reduce partial maxes (2048) -> global max ------------
__global__ __launch_bounds__(256) void k1b_reduce_max(
    const float* __restrict__ partialMax, float* __restrict__ gmax)
{
  const int t = threadIdx.x;
  float mx = -3.4e38f;
  for (int i = t; i < K12_BLOCKS; i += 256) mx = fmaxf(mx, partialMax[i]);
  mx = wave_max(mx);
  __shared__ float wmaxs[4];
  if ((t & 63) == 0) wmaxs[t >> 6] = mx;
  __syncthreads();
  if (t == 0)
    *gmax = fmaxf(fmaxf(wmaxs[0], wmaxs[1]), fmaxf(wmaxs[2], wmaxs[3]));
}

// ---------------- K2b: reduce -> kv values (LDS) -> ksF + kv B-fragments ----
__global__ __launch_bounds__(256) void k2b_reduce(
    const float* __restrict__ kvPart, const float* __restrict__ ksPart,
    const float* __restrict__ vsPart, const float* __restrict__ gmaxPtr,
    float* __restrict__ ksF, uint4* __restrict__ kfH, uint4* __restrict__ kfL)
{
  __shared__ float vsumL[64];
  __shared__ float kvL[2048];
  const int b = blockIdx.x, t = threadIdx.x;
  const float scale = __expf(-*gmaxPtr);
  if (t < 64) {
    float s = 0.f;
    for (int c = 0; c < CPB; ++c)
      s += vsPart[(b * CPB + c) * 64 + t];
    vsumL[t] = s;
  }
  __syncthreads();
  #pragma unroll
  for (int ii = 0; ii < 8; ++ii) {
    const int o = t + 256 * ii;
    float s = 0.f;
    for (int c = 0; c < CPB; ++c)
      s += kvPart[((size_t)(b * CPB + c)) * 2048 + o];
    kvL[o] = RATIO * (scale * s + EPSK * vsumL[o & 63]);
  }
  if (t < 32) {
    float s = 0.f;
    for (int c = 0; c < CPB; ++c)
      s += ksPart[(b * CPB + c) * 32 + t];
    ksF[b * 32 + t] = RATIO * (scale * s + EPSK * (float)NN);
  }
  __syncthreads();
  // B-frag (16x16x32): lane l holds kv[k=(l>>4)*8+j][d = dt*16 + (l&15)]
  {
    const int l = t & 63, dt = t >> 6;
    const int lr = l & 15, lg = l >> 4;
    float f[8];
    #pragma unroll
    for (int j = 0; j < 8; ++j)
      f[j] = kvL[(lg*8 + j)*64 + dt*16 + lr];
    FragU hi, lo; cvt8(f, hi, lo);
    kfH[(b*4 + dt)*64 + l] = hi.u;
    kfL[(b*4 + dt)*64 + l] = lo.u;
  }
}

// ---------------- K3: dash MFMA -> softmax -> num MFMA (barrier-free) -------
__global__ __launch_bounds__(256, 4) void k3_out(
    const float* __restrict__ q,
    const uint4* __restrict__ pfH, const uint4* __restrict__ pfL,
    const uint4* __restrict__ kfH, const uint4* __restrict__ kfL,
    const float* __restrict__ ksF, float* __restrict__ out)
{
  __shared__ float dashL[256][36];   // fp32 dash; reused per-row as packed pstar
  __shared__ float ssqL[256][4];
  const int t = threadIdx.x;
  const int w = t >> 6, l = t & 63;
  const int lr = l & 15, lg = l >> 4;
  const int b = blockIdx.x >> 5;
  const size_t rowBase = (size_t)blockIdx.x * 256;
  const int wrb = w * 64;

  FragU pbH[2][2], pbL[2][2];
  #pragma unroll
  for (int mt = 0; mt < 2; ++mt)
    #pragma unroll
    for (int ks = 0; ks < 2; ++ks) {
      pbH[mt][ks].u = pfH[(mt*2+ks)*64 + l];
      pbL[mt][ks].u = pfL[(mt*2+ks)*64 + l];
    }

  // phase A
  #pragma unroll
  for (int rt = 0; rt < 4; ++rt) {
    const int rrow = wrb + rt*16 + lr;
    f32x4 acc0 = {0.f,0.f,0.f,0.f}, acc1 = {0.f,0.f,0.f,0.f};
    float sq = 0.f;
    #pragma unroll
    for (int ks = 0; ks < 2; ++ks) {
      const float4* src = (const float4*)(q + (rowBase + rrow)*DD + ks*32 + lg*8);
      float4 a0 = src[0], a1 = src[1];
      float qv[8] = {a0.x,a0.y,a0.z,a0.w, a1.x,a1.y,a1.z,a1.w};
      #pragma unroll
      for (int j = 0; j < 8; ++j) sq += qv[j]*qv[j];
      FragU aH, aL; cvt8(qv, aH, aL);
      acc0 = MFMA(aL.s, pbH[0][ks].s, acc0);
      acc0 = MFMA(aH.s, pbL[0][ks].s, acc0);
      acc0 = MFMA(aH.s, pbH[0][ks].s, acc0);
      acc1 = MFMA(aL.s, pbH[1][ks].s, acc1);
      acc1 = MFMA(aH.s, pbL[1][ks].s, acc1);
      acc1 = MFMA(aH.s, pbH[1][ks].s, acc1);
    }
    ssqL[rrow][lg] = sq;
    #pragma unroll
    for (int reg = 0; reg < 4; ++reg) {
      dashL[wrb + rt*16 + lg*4 + reg][lr]      = acc0[reg];
      dashL[wrb + rt*16 + lg*4 + reg][16 + lr] = acc1[reg];
    }
  }

  // softmax phase: thread t owns row t (same wave as its stripe: no barrier)
  {
    float dv[32];
    const float4* dr = (const float4*)&dashL[t][0];
    #pragma unroll
    for (int i = 0; i < 8; ++i) {
      float4 v4 = dr[i];
      dv[4*i]=v4.x; dv[4*i+1]=v4.y; dv[4*i+2]=v4.z; dv[4*i+3]=v4.w;
    }
    const float ssq = ssqL[t][0]+ssqL[t][1]+ssqL[t][2]+ssqL[t][3];
    float mx = -3.4e38f;
    #pragma unroll
    for (int m = 0; m < MM; ++m) { dv[m] *= NORMC; mx = fmaxf(mx, dv[m]); }
    const float sub = DIAGC * ssq + mx;
    const float* __restrict__ ksb = ksF + b * 32;
    float den = 0.f;
    #pragma unroll
    for (int m = 0; m < MM; ++m) {
      dv[m] = RATIO * (__expf(dv[m] - sub) + EPSK);
      den = fmaf(dv[m], ksb[m], den);
    }
    const float inv = 1.0f / den;
    unsigned hiw[16], low[16];
    #pragma unroll
    for (int u = 0; u < 16; ++u) {
      const float x0 = dv[2*u] * inv, x1 = dv[2*u+1] * inv;
      const unsigned h0 = bf16r(x0);
      const unsigned l0 = bf16r(x0 - __uint_as_float(h0 << 16));
      const unsigned h1 = bf16r(x1);
      const unsigned l1 = bf16r(x1 - __uint_as_float(h1 << 16));
      hiw[u] = h0 | (h1 << 16);
      low[u] = l0 | (l1 << 16);
    }
    uint4* pr = (uint4*)&dashL[t][0];   // overwrite own row only
    pr[0] = make_uint4(hiw[0],hiw[1],hiw[2],hiw[3]);
    pr[1] = make_uint4(hiw[4],hiw[5],hiw[6],hiw[7]);
    pr[2] = make_uint4(hiw[8],hiw[9],hiw[10],hiw[11]);
    pr[3] = make_uint4(hiw[12],hiw[13],hiw[14],hiw[15]);
    pr[4] = make_uint4(low[0],low[1],low[2],low[3]);
    pr[5] = make_uint4(low[4],low[5],low[6],low[7]);
    pr[6] = make_uint4(low[8],low[9],low[10],low[11]);
    pr[7] = make_uint4(low[12],low[13],low[14],low[15]);
  }

  // phase B: out = pstar · kv (K=32, one k-step, 3 comp terms)
  FragU kbH[4], kbL[4];
  #pragma unroll
  for (int dt = 0; dt < 4; ++dt) {
    kbH[dt].u = kfH[(b*4 + dt)*64 + l];
    kbL[dt].u = kfL[(b*4 + dt)*64 + l];
  }
  #pragma unroll
  for (int rt = 0; rt < 4; ++rt) {
    const uint4* pr = (const uint4*)&dashL[wrb + rt*16 + lr][0];
    FragU aH, aL;
    aH.u = pr[lg];
    aL.u = pr[4 + lg];
    #pragma unroll
    for (int dt = 0; dt < 4; ++dt) {
      f32x4 o = {0.f,0.f,0.f,0.f};
      o = MFMA(aL.s, kbH[dt].s, o);
      o = MFMA(aH.s, kbL[dt].s, o);
      o = MFMA(aH.s, kbH[dt].s, o);
      float* ob = out + (rowBase + wrb + rt*16 + lg*4)*DD + dt*16 + lr;
      ob[0]      = o[0];
      ob[DD]     = o[1];
      ob[2*DD]   = o[2];
      ob[3*DD]   = o[3];
    }
  }
}

// ---------------- host ------------------------------------------------------
extern "C" void kernel_launch(void* const* d_in, const int* in_sizes, int n_in,
                              void* d_out, int out_size, void* d_ws, size_t ws_size,
                              hipStream_t stream) {
  const float* q    = (const float*)d_in[0];
  const float* k    = (const float*)d_in[1];
  const float* v    = (const float*)d_in[2];
  const float* proj = (const float*)d_in[3];
  float* out = (float*)d_out;
  float* ws  = (float*)d_ws;

  float*    partialMax = ws;                       // 2048
  float*    gmax       = ws + 2048;                // (pad to 4096)
  float*    kvPart     = ws + 4096;                // 2048*2048
  float*    ksPart     = kvPart + 4194304;         // 2048*32
  float*    vsPart     = ksPart + 65536;           // 2048*64
  float*    ksF        = vsPart + 131072;          // 64*32 (pad 2048)
  unsigned* pfH        = (unsigned*)(ksF + 2048);  // 4*64 uint4 = 1024 words
  unsigned* pfL        = pfH + 1024;               // 1024
  unsigned* kfH        = pfL + 1024;               // 64*4*64 uint4 = 65536 words
  unsigned* kfL        = kfH + 65536;              // 65536

  kfrag_proj<<<1, 256, 0, stream>>>(proj, (uint4*)pfH, (uint4*)pfL);
  k12_kv<<<K12_BLOCKS, 256, 0, stream>>>(k, v, (uint4*)pfH, (uint4*)pfL,
                                         kvPart, ksPart, vsPart, partialMax);
  k1b_reduce_max<<<1, 256, 0, stream>>>(partialMax, gmax);
  k2b_reduce<<<BH, 256, 0, stream>>>(kvPart, ksPart, vsPart, gmax,
                                     ksF, (uint4*)kfH, (uint4*)kfL);
  k3_out<<<NROWS / 256, 256, 0, stream>>>(q, (uint4*)pfH, (uint4*)pfL,
                                          (uint4*)kfH, (uint4*)kfL, ksF, out);
}

// Round 15
// 159.243 us; speedup vs baseline: 1.2043x; 1.2043x over previous
//
#include <hip/hip_runtime.h>
#include <math.h>

#define BH 64
#define NN 8192
#define DD 64
#define MM 32

#define NROWS (BH*NN)            // 524288
#define NORMC 0.35355339059327379f   // 64^-0.25
#define RATIO 0.17677669529663689f   // 32^-0.5
#define EPSK  1e-4f
#define DIAGC 0.0625f                // 0.5 * 64^-0.5

#define CPB 32                   // chunks per batch
#define CHUNK 256                // rows per chunk
#define K12_BLOCKS (BH*CPB)      // 2048

typedef __attribute__((ext_vector_type(8))) short short8;
typedef __attribute__((ext_vector_type(4))) float f32x4;

union FragU { uint4 u; short8 s; };

// round-to-nearest-even fp32 -> bf16 (bits in low 16)
__device__ __forceinline__ unsigned bf16r(float x) {
  unsigned u = __float_as_uint(x);
  return (u + 0x7fffu + ((u >> 16) & 1u)) >> 16;
}
// 8 fp32 -> hi/lo bf16x8 fragments (split: x = hi + lo)
__device__ __forceinline__ void cvt8(const float* f, FragU& hi, FragU& lo) {
  unsigned h[8], lw[8];
  #pragma unroll
  for (int j = 0; j < 8; ++j) {
    h[j] = bf16r(f[j]);
    lw[j] = bf16r(f[j] - __uint_as_float(h[j] << 16));
  }
  hi.u = make_uint4(h[0]|(h[1]<<16),  h[2]|(h[3]<<16),  h[4]|(h[5]<<16),  h[6]|(h[7]<<16));
  lo.u = make_uint4(lw[0]|(lw[1]<<16), lw[2]|(lw[3]<<16), lw[4]|(lw[5]<<16), lw[6]|(lw[7]<<16));
}

#define MFMA(a,b,c) __builtin_amdgcn_mfma_f32_16x16x32_bf16((a),(b),(c),0,0,0)

__device__ __forceinline__ float wave_max(float v) {
  #pragma unroll
  for (int off = 32; off > 0; off >>= 1)
    v = fmaxf(v, __shfl_down(v, off, 64));
  return v;
}

// ---------------- proj fragments: hi/lo bf16x8 per (mt,ks,lane) -------------
// B-frag (16x16x32): lane l holds B[k=(l>>4)*8+j][n=l&15]; B = proj^T so
// value = proj[mt*16 + (l&15)][ks*32 + (l>>4)*8 + j].
__global__ void kfrag_proj(const float* __restrict__ proj,
                           uint4* __restrict__ pfH, uint4* __restrict__ pfL)
{
  const int t = threadIdx.x;
  const int l = t & 63, g = t >> 6;          // g = mt*2 + ks
  const int mt = g >> 1, ks = g & 1;
  const int lr = l & 15, lg = l >> 4;
  float f[8];
  #pragma unroll
  for (int j = 0; j < 8; ++j)
    f[j] = proj[(mt*16 + lr)*DD + ks*32 + lg*8 + j];
  FragU hi, lo; cvt8(f, hi, lo);
  pfH[g*64 + l] = hi.u;
  pfL[g*64 + l] = lo.u;
}

// ---------------- K12: FUSED — dash MFMA -> E' (LDS bf16) -> kv MFMA --------
// R15: proj fragments are NOT register-resident. Each ks iteration reloads
// its 4 frags through an asm-laundered pointer (LICM can't hoist past the
// asm), so only 16 regs are live per ks instead of 32 persistent. Reloads
// are coalesced 16B loads from the hot 4KB L1-resident pf buffer, hidden
// under the 6 MFMAs. Phase-A peak ~95-110 regs <= 128 -> (256,4) without
// spill. Grid 2048 for backfill. WRITE_SIZE spill canary: legit ~18 MB.
__global__ __launch_bounds__(256, 4) void k12_kv(
    const float* __restrict__ k, const float* __restrict__ v,
    const uint4* __restrict__ pfH, const uint4* __restrict__ pfL,
    float* __restrict__ kvPart, float* __restrict__ ksPart,
    float* __restrict__ vsPart, float* __restrict__ partialMax)
{
  __shared__ float red[8192];      // 32 KB: aliased E' staging, then reductions
  __shared__ float wmaxL[4];
  const int t = threadIdx.x;
  const int w = t >> 6, l = t & 63;
  const int lr = l & 15, lg = l >> 4;
  const int blk = blockIdx.x;
  const int b = blk >> 5, c = blk & (CPB - 1);
  const size_t gbase = (size_t)b * NN + (size_t)c * CHUNK + (size_t)w * 64;

  ushort* eh = (ushort*)red + w * 2560;   // [32 m][40] hi  (2560B/wave)
  ushort* el = eh + 1280;                 // [32 m][40] lo

  f32x4 accK[2][4];
  #pragma unroll
  for (int mt = 0; mt < 2; ++mt)
    #pragma unroll
    for (int dt = 0; dt < 4; ++dt)
      accK[mt][dt] = (f32x4){0.f, 0.f, 0.f, 0.f};
  float ksacc0 = 0.f, ksacc1 = 0.f;
  float vsum[4] = {0.f, 0.f, 0.f, 0.f};
  float tmax = -3.4e38f;

  for (int nb = 0; nb < 2; ++nb) {
    const size_t nrow0 = gbase + nb * 32;

    // ---- phase A: E' for the nb's 32 rows (MFMA dash), staged to LDS
    #pragma unroll
    for (int rt = 0; rt < 2; ++rt) {
      float sq = 0.f;
      f32x4 a0 = {0.f,0.f,0.f,0.f}, a1 = {0.f,0.f,0.f,0.f};
      #pragma unroll
      for (int ks = 0; ks < 2; ++ks) {
        const float4* src = (const float4*)(k + (nrow0 + rt*16 + lr)*DD + ks*32 + lg*8);
        float4 x0 = src[0], x1 = src[1];
        float qv[8] = {x0.x,x0.y,x0.z,x0.w, x1.x,x1.y,x1.z,x1.w};
        #pragma unroll
        for (int j = 0; j < 8; ++j) sq += qv[j]*qv[j];
        FragU aH, aL; cvt8(qv, aH, aL);     // live only inside this ks

        // laundered per-ks proj-frag loads (16 regs live, not hoistable)
        uintptr_t pfh_ = (uintptr_t)pfH, pfl_ = (uintptr_t)pfL;
        asm volatile("" : "+s"(pfh_), "+s"(pfl_));
        const uint4* pH = (const uint4*)pfh_;
        const uint4* pL = (const uint4*)pfl_;
        FragU pH0, pH1, pL0, pL1;
        pH0.u = pH[ks*64 + l];          // mt=0: g = 0*2+ks
        pH1.u = pH[(2+ks)*64 + l];      // mt=1: g = 1*2+ks
        pL0.u = pL[ks*64 + l];
        pL1.u = pL[(2+ks)*64 + l];

        a0 = MFMA(aL.s, pH0.s, a0);
        a0 = MFMA(aH.s, pL0.s, a0);
        a0 = MFMA(aH.s, pH0.s, a0);
        a1 = MFMA(aL.s, pH1.s, a1);
        a1 = MFMA(aH.s, pL1.s, a1);
        a1 = MFMA(aH.s, pH1.s, a1);
      }
      sq += __shfl_xor(sq, 16, 64);
      sq += __shfl_xor(sq, 32, 64);
      unsigned h0w[4], l0w[4], h1w[4], l1w[4];
      #pragma unroll
      for (int reg = 0; reg < 4; ++reg) {
        const float diag = DIAGC * __shfl(sq, lg*4 + reg, 64);
        const float d0 = a0[reg] * NORMC;
        const float d1 = a1[reg] * NORMC;
        tmax = fmaxf(tmax, fmaxf(d0, d1));
        const float e0 = __expf(d0 - diag);
        const float e1 = __expf(d1 - diag);
        ksacc0 += e0;                      // col m = lr
        ksacc1 += e1;                      // col m = lr+16
        h0w[reg] = bf16r(e0);
        l0w[reg] = bf16r(e0 - __uint_as_float(h0w[reg] << 16));
        h1w[reg] = bf16r(e1);
        l1w[reg] = bf16r(e1 - __uint_as_float(h1w[reg] << 16));
      }
      const int nloc = rt*16 + lg*4;       // 4 consecutive ushorts, 4B-aligned
      *(unsigned*)(eh + lr*40      + nloc)     = h0w[0] | (h0w[1] << 16);
      *(unsigned*)(eh + lr*40      + nloc + 2) = h0w[2] | (h0w[3] << 16);
      *(unsigned*)(el + lr*40      + nloc)     = l0w[0] | (l0w[1] << 16);
      *(unsigned*)(el + lr*40      + nloc + 2) = l0w[2] | (l0w[3] << 16);
      *(unsigned*)(eh + (lr+16)*40 + nloc)     = h1w[0] | (h1w[1] << 16);
      *(unsigned*)(eh + (lr+16)*40 + nloc + 2) = h1w[2] | (h1w[3] << 16);
      *(unsigned*)(el + (lr+16)*40 + nloc)     = l1w[0] | (l1w[1] << 16);
      *(unsigned*)(el + (lr+16)*40 + nloc + 2) = l1w[2] | (l1w[3] << 16);
    }

    // ---- phase B: kv += E'^T x v via MFMA (A from LDS, B from global)
    #pragma unroll
    for (int dt = 0; dt < 4; ++dt) {
      float vv[8];
      #pragma unroll
      for (int j = 0; j < 8; ++j)
        vv[j] = v[(nrow0 + lg*8 + j)*DD + dt*16 + lr];
      vsum[dt] += vv[0]+vv[1]+vv[2]+vv[3]+vv[4]+vv[5]+vv[6]+vv[7];
      FragU bHv, bLv; cvt8(vv, bHv, bLv);
      #pragma unroll
      for (int mt = 0; mt < 2; ++mt) {
        FragU aHk, aLk;
        aHk.u = *(const uint4*)(eh + (mt*16 + lr)*40 + lg*8);
        aLk.u = *(const uint4*)(el + (mt*16 + lr)*40 + lg*8);
        accK[mt][dt] = MFMA(aLk.s, bHv.s, accK[mt][dt]);
        accK[mt][dt] = MFMA(aHk.s, bLv.s, accK[mt][dt]);
        accK[mt][dt] = MFMA(aHk.s, bHv.s, accK[mt][dt]);
      }
    }
  }

  // ---- epilogue: block max + reductions
  tmax = wave_max(tmax);
  if (l == 0) wmaxL[w] = tmax;
  ksacc0 += __shfl_xor(ksacc0, 16, 64);
  ksacc0 += __shfl_xor(ksacc0, 32, 64);
  ksacc1 += __shfl_xor(ksacc1, 16, 64);
  ksacc1 += __shfl_xor(ksacc1, 32, 64);
  #pragma unroll
  for (int dt = 0; dt < 4; ++dt) {
    vsum[dt] += __shfl_xor(vsum[dt], 16, 64);
    vsum[dt] += __shfl_xor(vsum[dt], 32, 64);
  }
  __syncthreads();                 // everyone done with E' staging
  // red layout [o][w] (o = m*64+d): lanes same inst -> banks 4lr+w, 2-way max
  #pragma unroll
  for (int mt = 0; mt < 2; ++mt)
    #pragma unroll
    for (int dt = 0; dt < 4; ++dt)
      #pragma unroll
      for (int reg = 0; reg < 4; ++reg)
        red[((mt*16 + lg*4 + reg)*64 + dt*16 + lr)*4 + w] = accK[mt][dt][reg];
  __syncthreads();
  if (t == 0)
    partialMax[blk] = fmaxf(fmaxf(wmaxL[0], wmaxL[1]), fmaxf(wmaxL[2], wmaxL[3]));
  #pragma unroll
  for (int ii = 0; ii < 8; ++ii) {
    const int o = t + 256 * ii;
    const float4 r4 = *(const float4*)&red[o*4];
    kvPart[(size_t)blk * 2048 + o] = r4.x + r4.y + r4.z + r4.w;
  }
  __syncthreads();
  if (l < 16) {
    red[w*32 + lr]        = ksacc0;
    red[w*32 + 16 + lr]   = ksacc1;
    #pragma unroll
    for (int dt = 0; dt < 4; ++dt)
      red[128 + w*64 + dt*16 + lr] = vsum[dt];
  }
  __syncthreads();
  if (t < 32)
    ksPart[blk*32 + t] = red[t] + red[32+t] + red[64+t] + red[96+t];
  if (t < 64)
    vsPart[blk*64 + t] = red[128+t] + red[192+t] + red[256+t] + red[320+t];
}

// ---------------- K1b: reduce partial maxes (2048) -> global max ------------
__global__ __launch_bounds__(256) void k1b_reduce_max(
    const float* __restrict__ partialMax, float* __restrict__ gmax)
{
  const int t = threadIdx.x;
  float mx = -3.4e38f;
  for (int i = t; i < K12_BLOCKS; i += 256) mx = fmaxf(mx, partialMax[i]);
  mx = wave_max(mx);
  __shared__ float wmaxs[4];
  if ((t & 63) == 0) wmaxs[t >> 6] = mx;
  __syncthreads();
  if (t == 0)
    *gmax = fmaxf(fmaxf(wmaxs[0], wmaxs[1]), fmaxf(wmaxs[2], wmaxs[3]));
}

// ---------------- K2b: reduce -> kv values (LDS) -> ksF + kv B-fragments ----
__global__ __launch_bounds__(256) void k2b_reduce(
    const float* __restrict__ kvPart, const float* __restrict__ ksPart,
    const float* __restrict__ vsPart, const float* __restrict__ gmaxPtr,
    float* __restrict__ ksF, uint4* __restrict__ kfH, uint4* __restrict__ kfL)
{
  __shared__ float vsumL[64];
  __shared__ float kvL[2048];
  const int b = blockIdx.x, t = threadIdx.x;
  const float scale = __expf(-*gmaxPtr);
  if (t < 64) {
    float s = 0.f;
    for (int c = 0; c < CPB; ++c)
      s += vsPart[(b * CPB + c) * 64 + t];
    vsumL[t] = s;
  }
  __syncthreads();
  #pragma unroll
  for (int ii = 0; ii < 8; ++ii) {
    const int o = t + 256 * ii;
    float s = 0.f;
    for (int c = 0; c < CPB; ++c)
      s += kvPart[((size_t)(b * CPB + c)) * 2048 + o];
    kvL[o] = RATIO * (scale * s + EPSK * vsumL[o & 63]);
  }
  if (t < 32) {
    float s = 0.f;
    for (int c = 0; c < CPB; ++c)
      s += ksPart[(b * CPB + c) * 32 + t];
    ksF[b * 32 + t] = RATIO * (scale * s + EPSK * (float)NN);
  }
  __syncthreads();
  // B-frag (16x16x32): lane l holds kv[k=(l>>4)*8+j][d = dt*16 + (l&15)]
  {
    const int l = t & 63, dt = t >> 6;
    const int lr = l & 15, lg = l >> 4;
    float f[8];
    #pragma unroll
    for (int j = 0; j < 8; ++j)
      f[j] = kvL[(lg*8 + j)*64 + dt*16 + lr];
    FragU hi, lo; cvt8(f, hi, lo);
    kfH[(b*4 + dt)*64 + l] = hi.u;
    kfL[(b*4 + dt)*64 + l] = lo.u;
  }
}

// ---------------- K3: dash MFMA -> softmax -> num MFMA (barrier-free) -------
__global__ __launch_bounds__(256, 4) void k3_out(
    const float* __restrict__ q,
    const uint4* __restrict__ pfH, const uint4* __restrict__ pfL,
    const uint4* __restrict__ kfH, const uint4* __restrict__ kfL,
    const float* __restrict__ ksF, float* __restrict__ out)
{
  __shared__ float dashL[256][36];   // fp32 dash; reused per-row as packed pstar
  __shared__ float ssqL[256][4];
  const int t = threadIdx.x;
  const int w = t >> 6, l = t & 63;
  const int lr = l & 15, lg = l >> 4;
  const int b = blockIdx.x >> 5;
  const size_t rowBase = (size_t)blockIdx.x * 256;
  const int wrb = w * 64;

  FragU pbH[2][2], pbL[2][2];
  #pragma unroll
  for (int mt = 0; mt < 2; ++mt)
    #pragma unroll
    for (int ks = 0; ks < 2; ++ks) {
      pbH[mt][ks].u = pfH[(mt*2+ks)*64 + l];
      pbL[mt][ks].u = pfL[(mt*2+ks)*64 + l];
    }

  // phase A
  #pragma unroll
  for (int rt = 0; rt < 4; ++rt) {
    const int rrow = wrb + rt*16 + lr;
    f32x4 acc0 = {0.f,0.f,0.f,0.f}, acc1 = {0.f,0.f,0.f,0.f};
    float sq = 0.f;
    #pragma unroll
    for (int ks = 0; ks < 2; ++ks) {
      const float4* src = (const float4*)(q + (rowBase + rrow)*DD + ks*32 + lg*8);
      float4 a0 = src[0], a1 = src[1];
      float qv[8] = {a0.x,a0.y,a0.z,a0.w, a1.x,a1.y,a1.z,a1.w};
      #pragma unroll
      for (int j = 0; j < 8; ++j) sq += qv[j]*qv[j];
      FragU aH, aL; cvt8(qv, aH, aL);
      acc0 = MFMA(aL.s, pbH[0][ks].s, acc0);
      acc0 = MFMA(aH.s, pbL[0][ks].s, acc0);
      acc0 = MFMA(aH.s, pbH[0][ks].s, acc0);
      acc1 = MFMA(aL.s, pbH[1][ks].s, acc1);
      acc1 = MFMA(aH.s, pbL[1][ks].s, acc1);
      acc1 = MFMA(aH.s, pbH[1][ks].s, acc1);
    }
    ssqL[rrow][lg] = sq;
    #pragma unroll
    for (int reg = 0; reg < 4; ++reg) {
      dashL[wrb + rt*16 + lg*4 + reg][lr]      = acc0[reg];
      dashL[wrb + rt*16 + lg*4 + reg][16 + lr] = acc1[reg];
    }
  }

  // softmax phase: thread t owns row t (same wave as its stripe: no barrier)
  {
    float dv[32];
    const float4* dr = (const float4*)&dashL[t][0];
    #pragma unroll
    for (int i = 0; i < 8; ++i) {
      float4 v4 = dr[i];
      dv[4*i]=v4.x; dv[4*i+1]=v4.y; dv[4*i+2]=v4.z; dv[4*i+3]=v4.w;
    }
    const float ssq = ssqL[t][0]+ssqL[t][1]+ssqL[t][2]+ssqL[t][3];
    float mx = -3.4e38f;
    #pragma unroll
    for (int m = 0; m < MM; ++m) { dv[m] *= NORMC; mx = fmaxf(mx, dv[m]); }
    const float sub = DIAGC * ssq + mx;
    const float* __restrict__ ksb = ksF + b * 32;
    float den = 0.f;
    #pragma unroll
    for (int m = 0; m < MM; ++m) {
      dv[m] = RATIO * (__expf(dv[m] - sub) + EPSK);
      den = fmaf(dv[m], ksb[m], den);
    }
    const float inv = 1.0f / den;
    unsigned hiw[16], low[16];
    #pragma unroll
    for (int u = 0; u < 16; ++u) {
      const float x0 = dv[2*u] * inv, x1 = dv[2*u+1] * inv;
      const unsigned h0 = bf16r(x0);
      const unsigned l0 = bf16r(x0 - __uint_as_float(h0 << 16));
      const unsigned h1 = bf16r(x1);
      const unsigned l1 = bf16r(x1 - __uint_as_float(h1 << 16));
      hiw[u] = h0 | (h1 << 16);
      low[u] = l0 | (l1 << 16);
    }
    uint4* pr = (uint4*)&dashL[t][0];   // overwrite own row only
    pr[0] = make_uint4(hiw[0],hiw[1],hiw[2],hiw[3]);
    pr[1] = make_uint4(hiw[4],hiw[5],hiw[6],hiw[7]);
    pr[2] = make_uint4(hiw[8],hiw[9],hiw[10],hiw[11]);
    pr[3] = make_uint4(hiw[12],hiw[13],hiw[14],hiw[15]);
    pr[4] = make_uint4(low[0],low[1],low[2],low[3]);
    pr[5] = make_uint4(low[4],low[5],low[6],low[7]);
    pr[6] = make_uint4(low[8],low[9],low[10],low[11]);
    pr[7] = make_uint4(low[12],low[13],low[14],low[15]);
  }

  // phase B: out = pstar · kv (K=32, one k-step, 3 comp terms)
  FragU kbH[4], kbL[4];
  #pragma unroll
  for (int dt = 0; dt < 4; ++dt) {
    kbH[dt].u = kfH[(b*4 + dt)*64 + l];
    kbL[dt].u = kfL[(b*4 + dt)*64 + l];
  }
  #pragma unroll
  for (int rt = 0; rt < 4; ++rt) {
    const uint4* pr = (const uint4*)&dashL[wrb + rt*16 + lr][0];
    FragU aH, aL;
    aH.u = pr[lg];
    aL.u = pr[4 + lg];
    #pragma unroll
    for (int dt = 0; dt < 4; ++dt) {
      f32x4 o = {0.f,0.f,0.f,0.f};
      o = MFMA(aL.s, kbH[dt].s, o);
      o = MFMA(aH.s, kbL[dt].s, o);
      o = MFMA(aH.s, kbH[dt].s, o);
      float* ob = out + (rowBase + wrb + rt*16 + lg*4)*DD + dt*16 + lr;
      ob[0]      = o[0];
      ob[DD]     = o[1];
      ob[2*DD]   = o[2];
      ob[3*DD]   = o[3];
    }
  }
}

// ---------------- host ------------------------------------------------------
extern "C" void kernel_launch(void* const* d_in, const int* in_sizes, int n_in,
                              void* d_out, int out_size, void* d_ws, size_t ws_size,
                              hipStream_t stream) {
  const float* q    = (const float*)d_in[0];
  const float* k    = (const float*)d_in[1];
  const float* v    = (const float*)d_in[2];
  const float* proj = (const float*)d_in[3];
  float* out = (float*)d_out;
  float* ws  = (float*)d_ws;

  float*    partialMax = ws;                       // 2048
  float*    gmax       = ws + 2048;                // (pad to 4096)
  float*    kvPart     = ws + 4096;                // 2048*2048
  float*    ksPart     = kvPart + 4194304;         // 2048*32
  float*    vsPart     = ksPart + 65536;           // 2048*64
  float*    ksF        = vsPart + 131072;          // 64*32 (pad 2048)
  unsigned* pfH        = (unsigned*)(ksF + 2048);  // 4*64 uint4 = 1024 words
  unsigned* pfL        = pfH + 1024;               // 1024
  unsigned* kfH        = pfL + 1024;               // 64*4*64 uint4 = 65536 words
  unsigned* kfL        = kfH + 65536;              // 65536

  kfrag_proj<<<1, 256, 0, stream>>>(proj, (uint4*)pfH, (uint4*)pfL);
  k12_kv<<<K12_BLOCKS, 256, 0, stream>>>(k, v, (uint4*)pfH, (uint4*)pfL,
                                         kvPart, ksPart, vsPart, partialMax);
  k1b_reduce_max<<<1, 256, 0, stream>>>(partialMax, gmax);
  k2b_reduce<<<BH, 256, 0, stream>>>(kvPart, ksPart, vsPart, gmax,
                                     ksF, (uint4*)kfH, (uint4*)kfL);
  k3_out<<<NROWS / 256, 256, 0, stream>>>(q, (uint4*)pfH, (uint4*)pfL,
                                          (uint4*)kfH, (uint4*)kfL, ksF, out);
}

// Round 16
// 149.822 us; speedup vs baseline: 1.2801x; 1.0629x over previous
//
#include <hip/hip_runtime.h>
#include <math.h>

#define BH 64
#define NN 8192
#define DD 64
#define MM 32

#define NROWS (BH*NN)            // 524288
#define NORMC 0.35355339059327379f   // 64^-0.25
#define RATIO 0.17677669529663689f   // 32^-0.5
#define EPSK  1e-4f
#define DIAGC 0.0625f                // 0.5 * 64^-0.5

#define CPB 32                   // chunks per batch
#define CHUNK 256                // rows per chunk
#define K12_BLOCKS (BH*CPB)      // 2048

typedef __attribute__((ext_vector_type(8))) short short8;
typedef __attribute__((ext_vector_type(4))) float f32x4;

union FragU { uint4 u; short8 s; };

// round-to-nearest-even fp32 -> bf16 (bits in low 16)
__device__ __forceinline__ unsigned bf16r(float x) {
  unsigned u = __float_as_uint(x);
  return (u + 0x7fffu + ((u >> 16) & 1u)) >> 16;
}
// 8 fp32 -> hi/lo bf16x8 fragments (split: x = hi + lo)
__device__ __forceinline__ void cvt8(const float* f, FragU& hi, FragU& lo) {
  unsigned h[8], lw[8];
  #pragma unroll
  for (int j = 0; j < 8; ++j) {
    h[j] = bf16r(f[j]);
    lw[j] = bf16r(f[j] - __uint_as_float(h[j] << 16));
  }
  hi.u = make_uint4(h[0]|(h[1]<<16),  h[2]|(h[3]<<16),  h[4]|(h[5]<<16),  h[6]|(h[7]<<16));
  lo.u = make_uint4(lw[0]|(lw[1]<<16), lw[2]|(lw[3]<<16), lw[4]|(lw[5]<<16), lw[6]|(lw[7]<<16));
}

#define MFMA(a,b,c) __builtin_amdgcn_mfma_f32_16x16x32_bf16((a),(b),(c),0,0,0)

__device__ __forceinline__ float wave_max(float v) {
  #pragma unroll
  for (int off = 32; off > 0; off >>= 1)
    v = fmaxf(v, __shfl_down(v, off, 64));
  return v;
}

// ---------------- proj fragments: hi/lo bf16x8 per (mt,ks,lane) -------------
// B-frag (16x16x32): lane l holds B[k=(l>>4)*8+j][n=l&15]; B = proj^T so
// value = proj[mt*16 + (l&15)][ks*32 + (l>>4)*8 + j].
__global__ void kfrag_proj(const float* __restrict__ proj,
                           uint4* __restrict__ pfH, uint4* __restrict__ pfL)
{
  const int t = threadIdx.x;
  const int l = t & 63, g = t >> 6;          // g = mt*2 + ks
  const int mt = g >> 1, ks = g & 1;
  const int lr = l & 15, lg = l >> 4;
  float f[8];
  #pragma unroll
  for (int j = 0; j < 8; ++j)
    f[j] = proj[(mt*16 + lr)*DD + ks*32 + lg*8 + j];
  FragU hi, lo; cvt8(f, hi, lo);
  pfH[g*64 + l] = hi.u;
  pfL[g*64 + l] = lo.u;
}

// ---------------- K12: FUSED — dash MFMA -> E' (LDS bf16) -> kv MFMA --------
// R16: grid 2048 (backfill, 8 blocks/CU queue) + launch_bounds(256,3)
// (~170-reg budget >= ~148 peak incl AGPR rounding -> ZERO spill; R14/R15
// showed (256,4)'s 128 budget always spills ~120-375 B/thread). Laundered
// per-ks proj-frag loads keep phase-A pressure minimal.
__global__ __launch_bounds__(256, 3) void k12_kv(
    const float* __restrict__ k, const float* __restrict__ v,
    const uint4* __restrict__ pfH, const uint4* __restrict__ pfL,
    float* __restrict__ kvPart, float* __restrict__ ksPart,
    float* __restrict__ vsPart, float* __restrict__ partialMax)
{
  __shared__ float red[8192];      // 32 KB: aliased E' staging, then reductions
  __shared__ float wmaxL[4];
  const int t = threadIdx.x;
  const int w = t >> 6, l = t & 63;
  const int lr = l & 15, lg = l >> 4;
  const int blk = blockIdx.x;
  const int b = blk >> 5, c = blk & (CPB - 1);
  const size_t gbase = (size_t)b * NN + (size_t)c * CHUNK + (size_t)w * 64;

  ushort* eh = (ushort*)red + w * 2560;   // [32 m][40] hi  (2560B/wave)
  ushort* el = eh + 1280;                 // [32 m][40] lo

  f32x4 accK[2][4];
  #pragma unroll
  for (int mt = 0; mt < 2; ++mt)
    #pragma unroll
    for (int dt = 0; dt < 4; ++dt)
      accK[mt][dt] = (f32x4){0.f, 0.f, 0.f, 0.f};
  float ksacc0 = 0.f, ksacc1 = 0.f;
  float vsum[4] = {0.f, 0.f, 0.f, 0.f};
  float tmax = -3.4e38f;

  for (int nb = 0; nb < 2; ++nb) {
    const size_t nrow0 = gbase + nb * 32;

    // ---- phase A: E' for the nb's 32 rows (MFMA dash), staged to LDS
    #pragma unroll
    for (int rt = 0; rt < 2; ++rt) {
      float sq = 0.f;
      f32x4 a0 = {0.f,0.f,0.f,0.f}, a1 = {0.f,0.f,0.f,0.f};
      #pragma unroll
      for (int ks = 0; ks < 2; ++ks) {
        const float4* src = (const float4*)(k + (nrow0 + rt*16 + lr)*DD + ks*32 + lg*8);
        float4 x0 = src[0], x1 = src[1];
        float qv[8] = {x0.x,x0.y,x0.z,x0.w, x1.x,x1.y,x1.z,x1.w};
        #pragma unroll
        for (int j = 0; j < 8; ++j) sq += qv[j]*qv[j];
        FragU aH, aL; cvt8(qv, aH, aL);     // live only inside this ks

        // laundered per-ks proj-frag loads (16 regs live, not hoistable)
        uintptr_t pfh_ = (uintptr_t)pfH, pfl_ = (uintptr_t)pfL;
        asm volatile("" : "+s"(pfh_), "+s"(pfl_));
        const uint4* pH = (const uint4*)pfh_;
        const uint4* pL = (const uint4*)pfl_;
        FragU pH0, pH1, pL0, pL1;
        pH0.u = pH[ks*64 + l];          // mt=0: g = 0*2+ks
        pH1.u = pH[(2+ks)*64 + l];      // mt=1: g = 1*2+ks
        pL0.u = pL[ks*64 + l];
        pL1.u = pL[(2+ks)*64 + l];

        a0 = MFMA(aL.s, pH0.s, a0);
        a0 = MFMA(aH.s, pL0.s, a0);
        a0 = MFMA(aH.s, pH0.s, a0);
        a1 = MFMA(aL.s, pH1.s, a1);
        a1 = MFMA(aH.s, pL1.s, a1);
        a1 = MFMA(aH.s, pH1.s, a1);
      }
      sq += __shfl_xor(sq, 16, 64);
      sq += __shfl_xor(sq, 32, 64);
      unsigned h0w[4], l0w[4], h1w[4], l1w[4];
      #pragma unroll
      for (int reg = 0; reg < 4; ++reg) {
        const float diag = DIAGC * __shfl(sq, lg*4 + reg, 64);
        const float d0 = a0[reg] * NORMC;
        const float d1 = a1[reg] * NORMC;
        tmax = fmaxf(tmax, fmaxf(d0, d1));
        const float e0 = __expf(d0 - diag);
        const float e1 = __expf(d1 - diag);
        ksacc0 += e0;                      // col m = lr
        ksacc1 += e1;                      // col m = lr+16
        h0w[reg] = bf16r(e0);
        l0w[reg] = bf16r(e0 - __uint_as_float(h0w[reg] << 16));
        h1w[reg] = bf16r(e1);
        l1w[reg] = bf16r(e1 - __uint_as_float(h1w[reg] << 16));
      }
      const int nloc = rt*16 + lg*4;       // 4 consecutive ushorts, 4B-aligned
      *(unsigned*)(eh + lr*40      + nloc)     = h0w[0] | (h0w[1] << 16);
      *(unsigned*)(eh + lr*40      + nloc + 2) = h0w[2] | (h0w[3] << 16);
      *(unsigned*)(el + lr*40      + nloc)     = l0w[0] | (l0w[1] << 16);
      *(unsigned*)(el + lr*40      + nloc + 2) = l0w[2] | (l0w[3] << 16);
      *(unsigned*)(eh + (lr+16)*40 + nloc)     = h1w[0] | (h1w[1] << 16);
      *(unsigned*)(eh + (lr+16)*40 + nloc + 2) = h1w[2] | (h1w[3] << 16);
      *(unsigned*)(el + (lr+16)*40 + nloc)     = l1w[0] | (l1w[1] << 16);
      *(unsigned*)(el + (lr+16)*40 + nloc + 2) = l1w[2] | (l1w[3] << 16);
    }

    // ---- phase B: kv += E'^T x v via MFMA (A from LDS, B from global)
    #pragma unroll
    for (int dt = 0; dt < 4; ++dt) {
      float vv[8];
      #pragma unroll
      for (int j = 0; j < 8; ++j)
        vv[j] = v[(nrow0 + lg*8 + j)*DD + dt*16 + lr];
      vsum[dt] += vv[0]+vv[1]+vv[2]+vv[3]+vv[4]+vv[5]+vv[6]+vv[7];
      FragU bHv, bLv; cvt8(vv, bHv, bLv);
      #pragma unroll
      for (int mt = 0; mt < 2; ++mt) {
        FragU aHk, aLk;
        aHk.u = *(const uint4*)(eh + (mt*16 + lr)*40 + lg*8);
        aLk.u = *(const uint4*)(el + (mt*16 + lr)*40 + lg*8);
        accK[mt][dt] = MFMA(aLk.s, bHv.s, accK[mt][dt]);
        accK[mt][dt] = MFMA(aHk.s, bLv.s, accK[mt][dt]);
        accK[mt][dt] = MFMA(aHk.s, bHv.s, accK[mt][dt]);
      }
    }
  }

  // ---- epilogue: block max + reductions
  tmax = wave_max(tmax);
  if (l == 0) wmaxL[w] = tmax;
  ksacc0 += __shfl_xor(ksacc0, 16, 64);
  ksacc0 += __shfl_xor(ksacc0, 32, 64);
  ksacc1 += __shfl_xor(ksacc1, 16, 64);
  ksacc1 += __shfl_xor(ksacc1, 32, 64);
  #pragma unroll
  for (int dt = 0; dt < 4; ++dt) {
    vsum[dt] += __shfl_xor(vsum[dt], 16, 64);
    vsum[dt] += __shfl_xor(vsum[dt], 32, 64);
  }
  __syncthreads();                 // everyone done with E' staging
  // red layout [o][w] (o = m*64+d): lanes same inst -> banks 4lr+w, 2-way max
  #pragma unroll
  for (int mt = 0; mt < 2; ++mt)
    #pragma unroll
    for (int dt = 0; dt < 4; ++dt)
      #pragma unroll
      for (int reg = 0; reg < 4; ++reg)
        red[((mt*16 + lg*4 + reg)*64 + dt*16 + lr)*4 + w] = accK[mt][dt][reg];
  __syncthreads();
  if (t == 0)
    partialMax[blk] = fmaxf(fmaxf(wmaxL[0], wmaxL[1]), fmaxf(wmaxL[2], wmaxL[3]));
  #pragma unroll
  for (int ii = 0; ii < 8; ++ii) {
    const int o = t + 256 * ii;
    const float4 r4 = *(const float4*)&red[o*4];
    kvPart[(size_t)blk * 2048 + o] = r4.x + r4.y + r4.z + r4.w;
  }
  __syncthreads();
  if (l < 16) {
    red[w*32 + lr]        = ksacc0;
    red[w*32 + 16 + lr]   = ksacc1;
    #pragma unroll
    for (int dt = 0; dt < 4; ++dt)
      red[128 + w*64 + dt*16 + lr] = vsum[dt];
  }
  __syncthreads();
  if (t < 32)
    ksPart[blk*32 + t] = red[t] + red[32+t] + red[64+t] + red[96+t];
  if (t < 64)
    vsPart[blk*64 + t] = red[128+t] + red[192+t] + red[256+t] + red[320+t];
}

// ---------------- K1b: reduce partial maxes (2048) -> global max ------------
__global__ __launch_bounds__(256) void k1b_reduce_max(
    const float* __restrict__ partialMax, float* __restrict__ gmax)
{
  const int t = threadIdx.x;
  float mx = -3.4e38f;
  for (int i = t; i < K12_BLOCKS; i += 256) mx = fmaxf(mx, partialMax[i]);
  mx = wave_max(mx);
  __shared__ float wmaxs[4];
  if ((t & 63) == 0) wmaxs[t >> 6] = mx;
  __syncthreads();
  if (t == 0)
    *gmax = fmaxf(fmaxf(wmaxs[0], wmaxs[1]), fmaxf(wmaxs[2], wmaxs[3]));
}

// ---------------- K2b: reduce -> kv values (LDS) -> ksF + kv B-fragments ----
__global__ __launch_bounds__(256) void k2b_reduce(
    const float* __restrict__ kvPart, const float* __restrict__ ksPart,
    const float* __restrict__ vsPart, const float* __restrict__ gmaxPtr,
    float* __restrict__ ksF, uint4* __restrict__ kfH, uint4* __restrict__ kfL)
{
  __shared__ float vsumL[64];
  __shared__ float kvL[2048];
  const int b = blockIdx.x, t = threadIdx.x;
  const float scale = __expf(-*gmaxPtr);
  if (t < 64) {
    float s = 0.f;
    for (int c = 0; c < CPB; ++c)
      s += vsPart[(b * CPB + c) * 64 + t];
    vsumL[t] = s;
  }
  __syncthreads();
  #pragma unroll
  for (int ii = 0; ii < 8; ++ii) {
    const int o = t + 256 * ii;
    float s = 0.f;
    for (int c = 0; c < CPB; ++c)
      s += kvPart[((size_t)(b * CPB + c)) * 2048 + o];
    kvL[o] = RATIO * (scale * s + EPSK * vsumL[o & 63]);
  }
  if (t < 32) {
    float s = 0.f;
    for (int c = 0; c < CPB; ++c)
      s += ksPart[(b * CPB + c) * 32 + t];
    ksF[b * 32 + t] = RATIO * (scale * s + EPSK * (float)NN);
  }
  __syncthreads();
  // B-frag (16x16x32): lane l holds kv[k=(l>>4)*8+j][d = dt*16 + (l&15)]
  {
    const int l = t & 63, dt = t >> 6;
    const int lr = l & 15, lg = l >> 4;
    float f[8];
    #pragma unroll
    for (int j = 0; j < 8; ++j)
      f[j] = kvL[(lg*8 + j)*64 + dt*16 + lr];
    FragU hi, lo; cvt8(f, hi, lo);
    kfH[(b*4 + dt)*64 + l] = hi.u;
    kfL[(b*4 + dt)*64 + l] = lo.u;
  }
}

// ---------------- K3: dash MFMA -> softmax -> num MFMA (barrier-free) -------
__global__ __launch_bounds__(256, 4) void k3_out(
    const float* __restrict__ q,
    const uint4* __restrict__ pfH, const uint4* __restrict__ pfL,
    const uint4* __restrict__ kfH, const uint4* __restrict__ kfL,
    const float* __restrict__ ksF, float* __restrict__ out)
{
  __shared__ float dashL[256][36];   // fp32 dash; reused per-row as packed pstar
  __shared__ float ssqL[256][4];
  const int t = threadIdx.x;
  const int w = t >> 6, l = t & 63;
  const int lr = l & 15, lg = l >> 4;
  const int b = blockIdx.x >> 5;
  const size_t rowBase = (size_t)blockIdx.x * 256;
  const int wrb = w * 64;

  FragU pbH[2][2], pbL[2][2];
  #pragma unroll
  for (int mt = 0; mt < 2; ++mt)
    #pragma unroll
    for (int ks = 0; ks < 2; ++ks) {
      pbH[mt][ks].u = pfH[(mt*2+ks)*64 + l];
      pbL[mt][ks].u = pfL[(mt*2+ks)*64 + l];
    }

  // phase A
  #pragma unroll
  for (int rt = 0; rt < 4; ++rt) {
    const int rrow = wrb + rt*16 + lr;
    f32x4 acc0 = {0.f,0.f,0.f,0.f}, acc1 = {0.f,0.f,0.f,0.f};
    float sq = 0.f;
    #pragma unroll
    for (int ks = 0; ks < 2; ++ks) {
      const float4* src = (const float4*)(q + (rowBase + rrow)*DD + ks*32 + lg*8);
      float4 a0 = src[0], a1 = src[1];
      float qv[8] = {a0.x,a0.y,a0.z,a0.w, a1.x,a1.y,a1.z,a1.w};
      #pragma unroll
      for (int j = 0; j < 8; ++j) sq += qv[j]*qv[j];
      FragU aH, aL; cvt8(qv, aH, aL);
      acc0 = MFMA(aL.s, pbH[0][ks].s, acc0);
      acc0 = MFMA(aH.s, pbL[0][ks].s, acc0);
      acc0 = MFMA(aH.s, pbH[0][ks].s, acc0);
      acc1 = MFMA(aL.s, pbH[1][ks].s, acc1);
      acc1 = MFMA(aH.s, pbL[1][ks].s, acc1);
      acc1 = MFMA(aH.s, pbH[1][ks].s, acc1);
    }
    ssqL[rrow][lg] = sq;
    #pragma unroll
    for (int reg = 0; reg < 4; ++reg) {
      dashL[wrb + rt*16 + lg*4 + reg][lr]      = acc0[reg];
      dashL[wrb + rt*16 + lg*4 + reg][16 + lr] = acc1[reg];
    }
  }

  // softmax phase: thread t owns row t (same wave as its stripe: no barrier)
  {
    float dv[32];
    const float4* dr = (const float4*)&dashL[t][0];
    #pragma unroll
    for (int i = 0; i < 8; ++i) {
      float4 v4 = dr[i];
      dv[4*i]=v4.x; dv[4*i+1]=v4.y; dv[4*i+2]=v4.z; dv[4*i+3]=v4.w;
    }
    const float ssq = ssqL[t][0]+ssqL[t][1]+ssqL[t][2]+ssqL[t][3];
    float mx = -3.4e38f;
    #pragma unroll
    for (int m = 0; m < MM; ++m) { dv[m] *= NORMC; mx = fmaxf(mx, dv[m]); }
    const float sub = DIAGC * ssq + mx;
    const float* __restrict__ ksb = ksF + b * 32;
    float den = 0.f;
    #pragma unroll
    for (int m = 0; m < MM; ++m) {
      dv[m] = RATIO * (__expf(dv[m] - sub) + EPSK);
      den = fmaf(dv[m], ksb[m], den);
    }
    const float inv = 1.0f / den;
    unsigned hiw[16], low[16];
    #pragma unroll
    for (int u = 0; u < 16; ++u) {
      const float x0 = dv[2*u] * inv, x1 = dv[2*u+1] * inv;
      const unsigned h0 = bf16r(x0);
      const unsigned l0 = bf16r(x0 - __uint_as_float(h0 << 16));
      const unsigned h1 = bf16r(x1);
      const unsigned l1 = bf16r(x1 - __uint_as_float(h1 << 16));
      hiw[u] = h0 | (h1 << 16);
      low[u] = l0 | (l1 << 16);
    }
    uint4* pr = (uint4*)&dashL[t][0];   // overwrite own row only
    pr[0] = make_uint4(hiw[0],hiw[1],hiw[2],hiw[3]);
    pr[1] = make_uint4(hiw[4],hiw[5],hiw[6],hiw[7]);
    pr[2] = make_uint4(hiw[8],hiw[9],hiw[10],hiw[11]);
    pr[3] = make_uint4(hiw[12],hiw[13],hiw[14],hiw[15]);
    pr[4] = make_uint4(low[0],low[1],low[2],low[3]);
    pr[5] = make_uint4(low[4],low[5],low[6],low[7]);
    pr[6] = make_uint4(low[8],low[9],low[10],low[11]);
    pr[7] = make_uint4(low[12],low[13],low[14],low[15]);
  }

  // phase B: out = pstar · kv (K=32, one k-step, 3 comp terms)
  FragU kbH[4], kbL[4];
  #pragma unroll
  for (int dt = 0; dt < 4; ++dt) {
    kbH[dt].u = kfH[(b*4 + dt)*64 + l];
    kbL[dt].u = kfL[(b*4 + dt)*64 + l];
  }
  #pragma unroll
  for (int rt = 0; rt < 4; ++rt) {
    const uint4* pr = (const uint4*)&dashL[wrb + rt*16 + lr][0];
    FragU aH, aL;
    aH.u = pr[lg];
    aL.u = pr[4 + lg];
    #pragma unroll
    for (int dt = 0; dt < 4; ++dt) {
      f32x4 o = {0.f,0.f,0.f,0.f};
      o = MFMA(aL.s, kbH[dt].s, o);
      o = MFMA(aH.s, kbL[dt].s, o);
      o = MFMA(aH.s, kbH[dt].s, o);
      float* ob = out + (rowBase + wrb + rt*16 + lg*4)*DD + dt*16 + lr;
      ob[0]      = o[0];
      ob[DD]     = o[1];
      ob[2*DD]   = o[2];
      ob[3*DD]   = o[3];
    }
  }
}

// ---------------- host ------------------------------------------------------
extern "C" void kernel_launch(void* const* d_in, const int* in_sizes, int n_in,
                              void* d_out, int out_size, void* d_ws, size_t ws_size,
                              hipStream_t stream) {
  const float* q    = (const float*)d_in[0];
  const float* k    = (const float*)d_in[1];
  const float* v    = (const float*)d_in[2];
  const float* proj = (const float*)d_in[3];
  float* out = (float*)d_out;
  float* ws  = (float*)d_ws;

  float*    partialMax = ws;                       // 2048
  float*    gmax       = ws + 2048;                // (pad to 4096)
  float*    kvPart     = ws + 4096;                // 2048*2048
  float*    ksPart     = kvPart + 4194304;         // 2048*32
  float*    vsPart     = ksPart + 65536;           // 2048*64
  float*    ksF        = vsPart + 131072;          // 64*32 (pad 2048)
  unsigned* pfH        = (unsigned*)(ksF + 2048);  // 4*64 uint4 = 1024 words
  unsigned* pfL        = pfH + 1024;               // 1024
  unsigned* kfH        = pfL + 1024;               // 64*4*64 uint4 = 65536 words
  unsigned* kfL        = kfH + 65536;              // 65536

  kfrag_proj<<<1, 256, 0, stream>>>(proj, (uint4*)pfH, (uint4*)pfL);
  k12_kv<<<K12_BLOCKS, 256, 0, stream>>>(k, v, (uint4*)pfH, (uint4*)pfL,
                                         kvPart, ksPart, vsPart, partialMax);
  k1b_reduce_max<<<1, 256, 0, stream>>>(partialMax, gmax);
  k2b_reduce<<<BH, 256, 0, stream>>>(kvPart, ksPart, vsPart, gmax,
                                     ksF, (uint4*)kfH, (uint4*)kfL);
  k3_out<<<NROWS / 256, 256, 0, stream>>>(q, (uint4*)pfH, (uint4*)pfL,
                                          (uint4*)kfH, (uint4*)kfL, ksF, out);
}